// Round 6
// baseline (489.230 us; speedup 1.0000x reference)
//
#include <hip/hip_runtime.h>

// GraphConvLayer: B=32, C=64, T=64, V=325, Ks=2. f32 in/out, bf16 MFMA compute.
// out[b,c,t,v] = x[b,c,t,v] + bias[c]
//              + sum_i W0[i,c] x[b,i,t,v]
//              + sum_i W1[i,c] * (sum_u x[b,i,t,u] gso[v,u])
//
// R6: t-batched software pipeline. Per-CU phase model showed stage1 (HBM),
// Phase A (L2 gfrag), Phase B (LDS+stores) serialize on different resources.
//  - 8 t's per block (grid 256, 1 block/CU, one round). Next-t x-loads are
//    issued into regs at Phase-B top (T14 split): HBM latency hides under
//    Phase B + barrier. Loads precede stores -> no vmcnt coupling.
//  - Phase A: one mt per wave with ALL 4 c-tiles sharing each ag frag:
//    gfrag L2 traffic per t halved (484->231 KB/CU), MFMA density doubled.
//  - mt/n tile count 22 -> 21 (ceil(325/16)); tile 21 was all-zero work.
//  - All R5-verified fragment mappings unchanged.

typedef __bf16 bf16x8 __attribute__((ext_vector_type(8)));
typedef float f32x4 __attribute__((ext_vector_type(4)));

#define XROW 360   // Xr row stride (elems): 180dw%32=20 -> benign banks
#define QROW 136   // XY row stride (elems): 68dw%32=4 -> benign banks
#define NFRAG 512  // elems per gso frag: 64 lanes x 8
#define NMT 21     // ceil(325/16)

__device__ __forceinline__ float bf2f(unsigned short u) {
  union { unsigned int i; float f; } t;
  t.i = ((unsigned int)u) << 16;
  return t.f;
}
__device__ __forceinline__ unsigned short f2bf_hw(float f) {
  __bf16 b = (__bf16)f;  // compiler emits HW bf16 cvt (RNE)
  union { __bf16 b; unsigned short u; } t;
  t.b = b;
  return t.u;
}

// gfrag[((mt*11+s)*64+l)*8+j] = gso[mt*16+(l&15)][s*32+(l>>4)*8+j] (0-padded)
// wt[k][c][i] = weight[k][i][c]
__global__ void prep_kernel(const float* __restrict__ gso,
                            const float* __restrict__ weight,
                            unsigned short* __restrict__ gfrag,
                            unsigned short* __restrict__ wt) {
  int idx = blockIdx.x * 256 + threadIdx.x;
  if (idx < 22 * 11 * NFRAG) {
    int fid = idx >> 9, r = idx & 511;
    int l = r >> 3, j = r & 7;
    int mt = fid / 11, s = fid - 11 * mt;
    int v = (mt << 4) + (l & 15);
    int u = (s << 5) + ((l >> 4) << 3) + j;
    unsigned short val = 0;
    if (v < 325 && u < 325) val = f2bf_hw(gso[v * 325 + u]);
    gfrag[idx] = val;
  }
  if (idx < 2 * 64 * 64) {
    int k = idx >> 12, r = idx & 4095, c = r >> 6, i = r & 63;
    wt[idx] = f2bf_hw(weight[(k << 12) | (i << 6) | c]);
  }
}

__global__ __launch_bounds__(1024, 4) void gconv_kernel(
    const float* __restrict__ x,
    const float* __restrict__ bias,
    const unsigned short* __restrict__ gfrag,
    const unsigned short* __restrict__ wt,
    float* __restrict__ out) {
  __shared__ unsigned short Xr[64 * XROW];   // 46080 B: x[c][u], u>=325 zero
  __shared__ unsigned short XY[352 * QROW];  // 95744 B: [u/v][ X c0..63 | Y c0..63 | pad ]

  const int bid = blockIdx.x;
  const int b = bid >> 3, tq = bid & 7;      // block owns t in [tq*8, tq*8+8)
  const int tid = threadIdx.x;
  const int wid = tid >> 6, lane = tid & 63;
  const int quad = lane >> 4, l16 = lane & 15;
  const int koff = quad * 8;  // A/B frag: k = s*32 + quad*8 + j

  // stage-thread mapping: thread owns c-row c1, u = u0 + 16k
  const int c1 = tid >> 4, u0 = tid & 15;
  const float* xrow0 = &x[(size_t)b * 1331200 + c1 * 20800 + (tq * 8) * 325];

  // Phase-B constants
  const int cb = (wid & 3) * 16;
  bf16x8 aW[4];  // A-frags: k-concat [W0 i0..63 | W1 i0..63]
#pragma unroll
  for (int s = 0; s < 4; ++s)
    aW[s] = *reinterpret_cast<const bf16x8*>(
        &wt[((s >> 1) * 64 + cb + l16) * 64 + (s & 1) * 32 + koff]);
  float bias_f[4];
#pragma unroll
  for (int r = 0; r < 4; ++r) bias_f[r] = bias[cb + quad * 4 + r];

  // ---- Prologue: issue staged x-loads for it=0 ----
  float xs[21];
#pragma unroll
  for (int k = 0; k < 20; ++k) xs[k] = xrow0[u0 + 16 * k];
  xs[20] = (u0 < 5) ? xrow0[u0 + 320] : 0.f;

  for (int it = 0; it < 8; ++it) {
    const int t = tq * 8 + it;
    const int xbase = b * 1331200 + t * 325;

    // ---- Stage write: regs -> bf16 Xr[c][u] + XY[u][c] (XY dead after prev B) ----
    {
      unsigned short* xrp = &Xr[c1 * XROW];
      unsigned short* xyc = &XY[c1];
#pragma unroll
      for (int k = 0; k < 21; ++k) {
        const int u = u0 + 16 * k;
        unsigned short us = f2bf_hw(xs[k]);
        xrp[u] = us;
        xyc[u * QROW] = us;
      }
      const int u = u0 + 336;  // pad tail [336,352) zero
      xrp[u] = 0;
      xyc[u * QROW] = 0;
    }
    __syncthreads();

    // ---- Phase A: XY[v][64+c] = sum_u gso[v,u]*x[c][u]; wave owns mt, all 4 c-tiles ----
    {
      const int mt0 = wid, mt1 = wid + 16;
      const bool two = (mt1 < NMT);  // wid < 5
      const unsigned short* gp0 = &gfrag[(mt0 * 11) * NFRAG + lane * 8];
      const unsigned short* gp1 = &gfrag[(mt1 * 11) * NFRAG + lane * 8];
      f32x4 acc0[4], acc1[4];
#pragma unroll
      for (int q = 0; q < 4; ++q) {
        acc0[q] = (f32x4){0.f, 0.f, 0.f, 0.f};
        acc1[q] = (f32x4){0.f, 0.f, 0.f, 0.f};
      }
#pragma unroll
      for (int s = 0; s < 11; ++s) {
        bf16x8 bXq[4];
#pragma unroll
        for (int q = 0; q < 4; ++q)
          bXq[q] = *reinterpret_cast<const bf16x8*>(
              &Xr[(q * 16 + l16) * XROW + s * 32 + koff]);
        bf16x8 ag0 = *reinterpret_cast<const bf16x8*>(gp0 + s * NFRAG);
#pragma unroll
        for (int q = 0; q < 4; ++q)
          acc0[q] = __builtin_amdgcn_mfma_f32_16x16x32_bf16(ag0, bXq[q], acc0[q], 0, 0, 0);
        if (two) {
          bf16x8 ag1 = *reinterpret_cast<const bf16x8*>(gp1 + s * NFRAG);
#pragma unroll
          for (int q = 0; q < 4; ++q)
            acc1[q] = __builtin_amdgcn_mfma_f32_16x16x32_bf16(ag1, bXq[q], acc1[q], 0, 0, 0);
        }
      }
      const int vr0 = mt0 * 16 + quad * 4;  // C/D: row = v, col = c
#pragma unroll
      for (int q = 0; q < 4; ++q)
#pragma unroll
        for (int r = 0; r < 4; ++r)
          XY[(vr0 + r) * QROW + 64 + q * 16 + l16] = f2bf_hw(acc0[q][r]);
      if (two) {
        const int vr1 = mt1 * 16 + quad * 4;
#pragma unroll
        for (int q = 0; q < 4; ++q)
#pragma unroll
          for (int r = 0; r < 4; ++r)
            XY[(vr1 + r) * QROW + 64 + q * 16 + l16] = f2bf_hw(acc1[q][r]);
      }
    }
    __syncthreads();

    // ---- Issue staged x-loads for it+1 (before Phase-B stores!) ----
    if (it < 7) {
      const float* xr = xrow0 + (it + 1) * 325;
#pragma unroll
      for (int k = 0; k < 20; ++k) xs[k] = xr[u0 + 16 * k];
      xs[20] = (u0 < 5) ? xr[u0 + 320] : 0.f;
      __builtin_amdgcn_sched_barrier(0);  // pin issue point; don't sink into B
    }

    // ---- Phase B: out[c][v] = W0^T@X + W1^T@Y + bias + residual ----
    for (int n = (wid >> 2); n < NMT; n += 4) {
      const int vb = n * 16;
      const unsigned short* xyp = &XY[(vb + l16) * QROW];
      bf16x8 bx0 = *reinterpret_cast<const bf16x8*>(xyp + koff);
      bf16x8 bx1 = *reinterpret_cast<const bf16x8*>(xyp + 32 + koff);
      bf16x8 by0 = *reinterpret_cast<const bf16x8*>(xyp + 64 + koff);
      bf16x8 by1 = *reinterpret_cast<const bf16x8*>(xyp + 96 + koff);
      f32x4 acc = {0.f, 0.f, 0.f, 0.f};
      acc = __builtin_amdgcn_mfma_f32_16x16x32_bf16(aW[0], bx0, acc, 0, 0, 0);
      acc = __builtin_amdgcn_mfma_f32_16x16x32_bf16(aW[1], bx1, acc, 0, 0, 0);
      acc = __builtin_amdgcn_mfma_f32_16x16x32_bf16(aW[2], by0, acc, 0, 0, 0);
      acc = __builtin_amdgcn_mfma_f32_16x16x32_bf16(aW[3], by1, acc, 0, 0, 0);
      const int v = vb + l16;  // C/D: col = v, row = c
      if (v < 325) {
        ushort4 rx = *reinterpret_cast<const ushort4*>(xyp + cb + quad * 4);
        const unsigned short rr[4] = {rx.x, rx.y, rx.z, rx.w};
#pragma unroll
        for (int r = 0; r < 4; ++r) {
          const int c = cb + quad * 4 + r;
          out[xbase + c * 20800 + v] = acc[r] + bias_f[r] + bf2f(rr[r]);
        }
      }
    }
    __syncthreads();  // XY/Xr dead -> next iter may overwrite
  }
}

extern "C" void kernel_launch(void* const* d_in, const int* in_sizes, int n_in,
                              void* d_out, int out_size, void* d_ws, size_t ws_size,
                              hipStream_t stream) {
  const float* x      = (const float*)d_in[0];
  const float* gso    = (const float*)d_in[1];
  const float* weight = (const float*)d_in[2];
  const float* bias   = (const float*)d_in[3];
  unsigned short* gfrag = (unsigned short*)d_ws;       // 22*11*512 bf16 = 352*352
  unsigned short* wt    = gfrag + 22 * 11 * NFRAG;     // 2*64*64 bf16

  prep_kernel<<<485, 256, 0, stream>>>(gso, weight, gfrag, wt);
  gconv_kernel<<<256, 1024, 0, stream>>>(x, bias, gfrag, wt, (float*)d_out);
}

// Round 7
// 467.379 us; speedup vs baseline: 1.0468x; 1.0468x over previous
//
#include <hip/hip_runtime.h>

// GraphConvLayer: B=32, C=64, T=64, V=325, Ks=2. f32 in/out, bf16 MFMA compute.
// out[b,c,t,v] = x[b,c,t,v] + bias[c]
//              + sum_i W0[i,c] x[b,i,t,v]
//              + sum_i W1[i,c] * (sum_u x[b,i,t,u] gso[v,u])
//
// R7 = R3 skeleton (2 blocks/CU, v-halved, Yt aliases Xr) + R5 lean internals.
// R6 post-mortem: reg-staging spilled to scratch (+344MB HBM traffic) -> revert.
//  - v-half blocks (grid 4096, h=bid&1): Xt/Yt 176 rows = 25.3 KB each.
//  - LDS = Xr 46.1K (aliased by Yt) + Xt 25.3K = 71.4 KB -> 2 blocks/CU,
//    launch_bounds(1024,8); cross-block phase overlap fills stall holes.
//  - stage-1 dual-writes Xr[c][u] + Xt[vl][c] (no transpose pass), HW bf16 cvt.
//  - Phase A: R5's pre-swizzled gfrag (64-lane coalesced 1KB A-frag loads);
//    bX[11] preloaded to regs before Yt overwrites Xr.
//  - 21 m-tiles total (h=0: 11, h=1: 10); all-zero tile 21 dropped.

typedef __bf16 bf16x8 __attribute__((ext_vector_type(8)));
typedef float f32x4 __attribute__((ext_vector_type(4)));

#define XROW 360   // Xr row stride (elems): 180dw%32=20 -> benign banks
#define TROW 72    // Xt/Yt row stride: 36dw%32=4 -> benign banks
#define NFRAG 512  // elems per gso frag: 64 lanes x 8

__device__ __forceinline__ float bf2f(unsigned short u) {
  union { unsigned int i; float f; } t;
  t.i = ((unsigned int)u) << 16;
  return t.f;
}
__device__ __forceinline__ unsigned short f2bf_hw(float f) {
  __bf16 b = (__bf16)f;  // compiler emits HW bf16 cvt (RNE)
  union { __bf16 b; unsigned short u; } t;
  t.b = b;
  return t.u;
}

// gfrag[((mt*11+s)*64+l)*8+j] = gso[mt*16+(l&15)][s*32+(l>>4)*8+j] (0-padded)
// wt[k][c][i] = weight[k][i][c]
__global__ void prep_kernel(const float* __restrict__ gso,
                            const float* __restrict__ weight,
                            unsigned short* __restrict__ gfrag,
                            unsigned short* __restrict__ wt) {
  int idx = blockIdx.x * 256 + threadIdx.x;
  if (idx < 22 * 11 * NFRAG) {
    int fid = idx >> 9, r = idx & 511;
    int l = r >> 3, j = r & 7;
    int mt = fid / 11, s = fid - 11 * mt;
    int v = (mt << 4) + (l & 15);
    int u = (s << 5) + ((l >> 4) << 3) + j;
    unsigned short val = 0;
    if (v < 325 && u < 325) val = f2bf_hw(gso[v * 325 + u]);
    gfrag[idx] = val;
  }
  if (idx < 2 * 64 * 64) {
    int k = idx >> 12, r = idx & 4095, c = r >> 6, i = r & 63;
    wt[idx] = f2bf_hw(weight[(k << 12) | (i << 6) | c]);
  }
}

__global__ __launch_bounds__(1024, 8) void gconv_kernel(
    const float* __restrict__ x,
    const float* __restrict__ bias,
    const unsigned short* __restrict__ gfrag,
    const unsigned short* __restrict__ wt,
    float* __restrict__ out) {
  // Xr: x[c][u] (stage1..preload), aliased as Yt[176][TROW] from Phase A on.
  __shared__ unsigned short Xr[64 * XROW];   // 46080 B
  __shared__ unsigned short Xt[176 * TROW];  // 25344 B: x^T[vl][c], this v-half
  unsigned short* const Yt = Xr;

  const int bid = blockIdx.x;
  const int h = bid & 1;           // v-half: tiles [h*11, h*11 + nmt)
  const int bt = bid >> 1;
  const int b = bt >> 6, t = bt & 63;
  const int nmt = 11 - h;          // h=0: 11 tiles (v 0..175), h=1: 10 (v 176..335)
  const int voff = h * 176;
  const int tid = threadIdx.x;
  const int xbase = b * 1331200 + t * 325;  // + c*20800 + v (f32 elems)

  // ---- Stage 1: global f32 -> bf16, dual-write Xr[c][u] + Xt[vl][c] ----
  {
    const int c1 = tid >> 4;       // thread owns c-row c1, u = u0 + 16k
    const int u0 = tid & 15;
    const float* xrow = &x[xbase + c1 * 20800];
    unsigned short* xrp = &Xr[c1 * XROW];
#pragma unroll
    for (int k = 0; k < 22; ++k) {
      const int u = u0 + 16 * k;
      float val = (u < 325) ? xrow[u] : 0.f;
      unsigned short us = f2bf_hw(val);
      xrp[u] = us;
      const int vl = u - voff;     // wave-uniform branch per k (16-aligned ranges)
      if (vl >= 0 && vl < 176) Xt[vl * TROW + c1] = us;
    }
  }
  __syncthreads();

  const int wid = tid >> 6, lane = tid & 63;
  const int quad = lane >> 4, l16 = lane & 15;
  const int koff = quad * 8;  // A/B frag: k = s*32 + quad*8 + j

  // ---- Preload Phase-A B-frags from Xr (regs) before Yt overwrites it ----
  const int cn = (wid & 3) * 16;  // this wave's c-tile (Phase A and B)
  bf16x8 bX[11];
#pragma unroll
  for (int s = 0; s < 11; ++s)
    bX[s] = *reinterpret_cast<const bf16x8*>(&Xr[(cn + l16) * XROW + s * 32 + koff]);
  __syncthreads();  // all Xr reads done; buf is now Yt

  // ---- Phase A: Yt[vl][c] = sum_u gso[voff+vl,u] * x[c][u]  (M=v, N=c, K=352) ----
  for (int lt = (wid >> 2); lt < nmt; lt += 4) {
    const int mt = h * 11 + lt;
    const unsigned short* gp = &gfrag[(mt * 11) * NFRAG + lane * 8];
    f32x4 acc = {0.f, 0.f, 0.f, 0.f};
#pragma unroll
    for (int s = 0; s < 11; ++s) {
      // A-frag: 64 lanes contiguous, 1KB coalesced, L2-hot
      bf16x8 ag = *reinterpret_cast<const bf16x8*>(gp + s * NFRAG);
      acc = __builtin_amdgcn_mfma_f32_16x16x32_bf16(ag, bX[s], acc, 0, 0, 0);
    }
    const int vlr = lt * 16 + quad * 4;  // C/D: row = local v, col = c
#pragma unroll
    for (int r = 0; r < 4; ++r)
      Yt[(vlr + r) * TROW + cn + l16] = f2bf_hw(acc[r]);  // lanes contiguous
  }
  __syncthreads();

  // ---- Phase B: out[c][v] = W0^T@X + W1^T@Y + bias + residual ----
  {
    const int cb = (wid & 3) * 16;  // m-tile (c)
    bf16x8 aW[4];                   // A-frags: k-concat [W0 i0..63 | W1 i0..63]
#pragma unroll
    for (int s = 0; s < 4; ++s)
      aW[s] = *reinterpret_cast<const bf16x8*>(
          &wt[((s >> 1) * 64 + cb + l16) * 64 + (s & 1) * 32 + koff]);
    float bias_f[4];
#pragma unroll
    for (int r = 0; r < 4; ++r) bias_f[r] = bias[cb + quad * 4 + r];

    for (int nloc = (wid >> 2); nloc < nmt; nloc += 4) {
      const int vbl = nloc * 16;
      const unsigned short* tp = &Xt[(vbl + l16) * TROW + koff];
      const unsigned short* yp = &Yt[(vbl + l16) * TROW + koff];
      bf16x8 bx0 = *reinterpret_cast<const bf16x8*>(tp);
      bf16x8 bx1 = *reinterpret_cast<const bf16x8*>(tp + 32);
      bf16x8 by0 = *reinterpret_cast<const bf16x8*>(yp);
      bf16x8 by1 = *reinterpret_cast<const bf16x8*>(yp + 32);
      f32x4 acc = {0.f, 0.f, 0.f, 0.f};
      acc = __builtin_amdgcn_mfma_f32_16x16x32_bf16(aW[0], bx0, acc, 0, 0, 0);
      acc = __builtin_amdgcn_mfma_f32_16x16x32_bf16(aW[1], bx1, acc, 0, 0, 0);
      acc = __builtin_amdgcn_mfma_f32_16x16x32_bf16(aW[2], by0, acc, 0, 0, 0);
      acc = __builtin_amdgcn_mfma_f32_16x16x32_bf16(aW[3], by1, acc, 0, 0, 0);
      const int v = voff + vbl + l16;  // C/D: col = v, row = c
      if (v < 325) {
        // residual: bf16-rounded x[c][v] from Xt (8B aligned)
        ushort4 rx = *reinterpret_cast<const ushort4*>(
            &Xt[(vbl + l16) * TROW + cb + quad * 4]);
        const unsigned short rr[4] = {rx.x, rx.y, rx.z, rx.w};
#pragma unroll
        for (int r = 0; r < 4; ++r) {
          const int c = cb + quad * 4 + r;
          out[xbase + c * 20800 + v] = acc[r] + bias_f[r] + bf2f(rr[r]);
        }
      }
    }
  }
}

extern "C" void kernel_launch(void* const* d_in, const int* in_sizes, int n_in,
                              void* d_out, int out_size, void* d_ws, size_t ws_size,
                              hipStream_t stream) {
  const float* x      = (const float*)d_in[0];
  const float* gso    = (const float*)d_in[1];
  const float* weight = (const float*)d_in[2];
  const float* bias   = (const float*)d_in[3];
  unsigned short* gfrag = (unsigned short*)d_ws;       // 22*11*512 bf16 = 352*352
  unsigned short* wt    = gfrag + 22 * 11 * NFRAG;     // 2*64*64 bf16

  prep_kernel<<<485, 256, 0, stream>>>(gso, weight, gfrag, wt);
  gconv_kernel<<<4096, 1024, 0, stream>>>(x, bias, gfrag, wt, (float*)d_out);
}

// Round 8
// 443.553 us; speedup vs baseline: 1.1030x; 1.0537x over previous
//
#include <hip/hip_runtime.h>

// GraphConvLayer: B=32, C=64, T=64, V=325, Ks=2. f32 in/out, bf16 MFMA compute.
// out[b,c,t,v] = x[b,c,t,v] + bias[c]
//              + sum_i W0[i,c] x[b,i,t,v]
//              + sum_i W1[i,c] * (sum_u x[b,i,t,u] gso[v,u])
//
// R8: reassociation  W1^T(X G^T) = (W1^T X) G^T.
//  - Phase A': Z = W1^T X and P0 = W0^T X (K=64, B-frags = Xt row-reads,
//    A-frags = verified wt packing). P0 has the same (c,v)-tile decomposition
//    as the output -> kept in REGISTERS across the barrier (no LDS round-trip).
//  - Phase B': out = P0 + Z G^T + bias + x. A-frags zA[11] = Z rows, loaded
//    once per wave and reused across all its v-tiles; B-frags = gfrag array
//    UNCHANGED (lane=v / k=u packing is exactly the B-operand layout; A/B
//    frags are lane-symmetric). gfrag L2 traffic 484 -> 231 KB/block (1x).
//  - Xr eliminated: only Xt staged (LDS 141.8 -> 89.6 KB), 2 barriers,
//    x read once. All fragment mappings byte-identical to verified R5/R7 code.
//  - R7 lesson: occupancy is off the table; stay 1 blk/CU, VGPR cap 128.

typedef __bf16 bf16x8 __attribute__((ext_vector_type(8)));
typedef float f32x4 __attribute__((ext_vector_type(4)));

#define XTROW 68   // Xt row stride (elems): 34dw%32=2 -> 2-way max on row-reads
#define ZROW 360   // Z row stride (elems): 180dw%32=20 -> benign (Xr-proven)
#define NFRAG 512  // elems per gso frag: 64 lanes x 8
#define NMT 21     // ceil(325/16) v-tiles

__device__ __forceinline__ float bf2f(unsigned short u) {
  union { unsigned int i; float f; } t;
  t.i = ((unsigned int)u) << 16;
  return t.f;
}
__device__ __forceinline__ unsigned short f2bf_hw(float f) {
  __bf16 b = (__bf16)f;  // compiler emits HW bf16 cvt (RNE)
  union { __bf16 b; unsigned short u; } t;
  t.b = b;
  return t.u;
}

// gfrag[((mt*11+s)*64+l)*8+j] = gso[mt*16+(l&15)][s*32+(l>>4)*8+j] (0-padded)
// wt[k][c][i] = weight[k][i][c]
__global__ void prep_kernel(const float* __restrict__ gso,
                            const float* __restrict__ weight,
                            unsigned short* __restrict__ gfrag,
                            unsigned short* __restrict__ wt) {
  int idx = blockIdx.x * 256 + threadIdx.x;
  if (idx < 22 * 11 * NFRAG) {
    int fid = idx >> 9, r = idx & 511;
    int l = r >> 3, j = r & 7;
    int mt = fid / 11, s = fid - 11 * mt;
    int v = (mt << 4) + (l & 15);
    int u = (s << 5) + ((l >> 4) << 3) + j;
    unsigned short val = 0;
    if (v < 325 && u < 325) val = f2bf_hw(gso[v * 325 + u]);
    gfrag[idx] = val;
  }
  if (idx < 2 * 64 * 64) {
    int k = idx >> 12, r = idx & 4095, c = r >> 6, i = r & 63;
    wt[idx] = f2bf_hw(weight[(k << 12) | (i << 6) | c]);
  }
}

__global__ __launch_bounds__(1024, 4) void gconv_kernel(
    const float* __restrict__ x,
    const float* __restrict__ bias,
    const unsigned short* __restrict__ gfrag,
    const unsigned short* __restrict__ wt,
    float* __restrict__ out) {
  __shared__ unsigned short Xt[336 * XTROW];  // 45696 B: x^T[v][c], rows 325..335 zero
  __shared__ unsigned short Z[64 * ZROW];     // 46080 B: Z[c][u], cols 336..359 zero

  const int bid = blockIdx.x;
  const int b = bid >> 6, t = bid & 63;
  const int tid = threadIdx.x;
  const int xbase = b * 1331200 + t * 325;  // + c*20800 + v (f32 elems)

  // ---- Stage 1: global f32 -> bf16 Xt[v][c] (transposed write only) ----
  {
    const int c1 = tid >> 4;       // thread owns c-row c1, u = u0 + 16k
    const int u0 = tid & 15;
    const float* xrow = &x[xbase + c1 * 20800];
#pragma unroll
    for (int k = 0; k < 21; ++k) { // u = 0..335 exactly
      const int u = u0 + 16 * k;
      float val = (u < 325) ? xrow[u] : 0.f;
      Xt[u * XTROW + c1] = f2bf_hw(val);
    }
  }
  // zero Z tail cols [336,360) so zA[s=10] reads are clean
  for (int i = tid; i < 64 * 24; i += 1024)
    Z[(i / 24) * ZROW + 336 + (i % 24)] = 0;
  __syncthreads();

  const int wid = tid >> 6, lane = tid & 63;
  const int quad = lane >> 4, l16 = lane & 15;
  const int koff = quad * 8;      // A/B frag: k = s*32 + quad*8 + j
  const int cb = (wid & 3) * 16;  // this wave's c-tile (all phases)
  const int w4 = wid >> 2;        // v-tile stride class: nt = w4 + 4j

  // A-frags: W0/W1 in verified wt packing (lane l16 = m = c_out, k = i)
  bf16x8 aW0[2], aW1[2];
#pragma unroll
  for (int s = 0; s < 2; ++s) {
    aW0[s] = *reinterpret_cast<const bf16x8*>(&wt[(cb + l16) * 64 + s * 32 + koff]);
    aW1[s] = *reinterpret_cast<const bf16x8*>(&wt[(64 + cb + l16) * 64 + s * 32 + koff]);
  }

  // ---- Phase A': Z[c][u] = W1^T X (-> LDS), P0 = W0^T X (-> regs) ----
  f32x4 p0[6];
#pragma unroll
  for (int j = 0; j < 6; ++j) {
    p0[j] = (f32x4){0.f, 0.f, 0.f, 0.f};
    const int nt = w4 + 4 * j;
    if (nt < NMT) {
      const unsigned short* tp = &Xt[(nt * 16 + l16) * XTROW];
      bf16x8 b0 = *reinterpret_cast<const bf16x8*>(tp + koff);        // k=c 0..31
      bf16x8 b1 = *reinterpret_cast<const bf16x8*>(tp + 32 + koff);   // k=c 32..63
      f32x4 z = {0.f, 0.f, 0.f, 0.f};
      z = __builtin_amdgcn_mfma_f32_16x16x32_bf16(aW1[0], b0, z, 0, 0, 0);
      z = __builtin_amdgcn_mfma_f32_16x16x32_bf16(aW1[1], b1, z, 0, 0, 0);
      p0[j] = __builtin_amdgcn_mfma_f32_16x16x32_bf16(aW0[0], b0, p0[j], 0, 0, 0);
      p0[j] = __builtin_amdgcn_mfma_f32_16x16x32_bf16(aW0[1], b1, p0[j], 0, 0, 0);
      // C/D: row = c = cb+quad*4+r, col = u = nt*16+l16 (lanes contiguous)
#pragma unroll
      for (int r = 0; r < 4; ++r)
        Z[(cb + quad * 4 + r) * ZROW + nt * 16 + l16] = f2bf_hw(z[r]);
    }
  }
  __syncthreads();

  // ---- Phase B': out[c][v] = P0 + Z G^T + bias + residual ----
  {
    // zA: Z rows (lane l16 = m = c_out), loaded once, reused across v-tiles
    bf16x8 zA[11];
#pragma unroll
    for (int s = 0; s < 11; ++s)
      zA[s] = *reinterpret_cast<const bf16x8*>(&Z[(cb + l16) * ZROW + s * 32 + koff]);
    float bias_f[4];
#pragma unroll
    for (int r = 0; r < 4; ++r) bias_f[r] = bias[cb + quad * 4 + r];

#pragma unroll
    for (int j = 0; j < 6; ++j) {
      const int nt = w4 + 4 * j;
      if (nt < NMT) {
        const int vb = nt * 16;
        const unsigned short* gp = &gfrag[(nt * 11) * NFRAG + lane * 8];
        f32x4 acc = p0[j];
#pragma unroll
        for (int s = 0; s < 11; ++s) {
          // B-frag: gfrag unchanged (lane l16 = n = v, k = u); 1KB coalesced L2
          bf16x8 bg = *reinterpret_cast<const bf16x8*>(gp + s * NFRAG);
          acc = __builtin_amdgcn_mfma_f32_16x16x32_bf16(zA[s], bg, acc, 0, 0, 0);
        }
        const int v = vb + l16;  // C/D: col = v, row = c
        if (v < 325) {
          // residual: bf16-rounded x[c][v] from Xt (8B-aligned ushort4)
          ushort4 rx = *reinterpret_cast<const ushort4*>(
              &Xt[(vb + l16) * XTROW + cb + quad * 4]);
          const unsigned short rr[4] = {rx.x, rx.y, rx.z, rx.w};
#pragma unroll
          for (int r = 0; r < 4; ++r) {
            const int c = cb + quad * 4 + r;
            out[xbase + c * 20800 + v] = acc[r] + bias_f[r] + bf2f(rr[r]);
          }
        }
      }
    }
  }
}

extern "C" void kernel_launch(void* const* d_in, const int* in_sizes, int n_in,
                              void* d_out, int out_size, void* d_ws, size_t ws_size,
                              hipStream_t stream) {
  const float* x      = (const float*)d_in[0];
  const float* gso    = (const float*)d_in[1];
  const float* weight = (const float*)d_in[2];
  const float* bias   = (const float*)d_in[3];
  unsigned short* gfrag = (unsigned short*)d_ws;       // 22*11*512 bf16 = 352*352
  unsigned short* wt    = gfrag + 22 * 11 * NFRAG;     // 2*64*64 bf16

  prep_kernel<<<485, 256, 0, stream>>>(gso, weight, gfrag, wt);
  gconv_kernel<<<2048, 1024, 0, stream>>>(x, bias, gfrag, wt, (float*)d_out);
}